// Round 3
// baseline (2045.377 us; speedup 1.0000x reference)
//
#include <hip/hip_runtime.h>
#include <cstdint>
#include <climits>

#define N 8192
#define D 64
#define H 128
#define O 64
#define KNB 16
#define NE (N*KNB)        // 131072
#define ETOT (NE + N)     // 139264
#define OUT0 (N*D)        // 524288

__device__ __forceinline__ float bf2f(unsigned short u){
    union { unsigned int u; float f; } v; v.u = ((unsigned int)u) << 16; return v.f;
}
__device__ __forceinline__ unsigned short f2bf(float f){
    union { float f; unsigned int u; } v; v.f = f;
    unsigned int r = v.u + 0x7FFFu + ((v.u >> 16) & 1u);   // RNE
    return (unsigned short)(r >> 16);
}

// ---------------- dtype probe: 1=bf16 inputs, 0=fp32 inputs ----------------
__global__ void k_probe(const unsigned short* __restrict__ x, int* __restrict__ flag){
    __shared__ int cnt;
    if (threadIdx.x == 0) cnt = 0;
    __syncthreads();
    unsigned short u = x[2*threadIdx.x];
    int e = (u >> 7) & 0xFF;
    int ok = (u == 0) || (e >= 0x60 && e <= 0x85);
    unsigned long long m = __ballot(ok);
    if ((threadIdx.x & 63) == 0) atomicAdd(&cnt, __popcll(m));
    __syncthreads();
    if (threadIdx.x == 0) *flag = (cnt >= 128) ? 1 : 0;
}

// ---------------- generic input convert -> fp32 ----------------
__global__ void k_cvt(const void* __restrict__ src, float* __restrict__ dst,
                      int n, const int* __restrict__ flag){
    int i = blockIdx.x*256 + threadIdx.x;
    if (i >= n) return;
    if (*flag) dst[i] = bf2f(((const unsigned short*)src)[i]);
    else       dst[i] = ((const float*)src)[i];
}

// ---------------- row norms: EXACT numpy fp32 pairwise semantics ----------------
// np.linalg.norm(x,axis=1): square elementwise (fp32), pairwise add.reduce
// (n=64 -> 8 strided accumulators, ((r0+r1)+(r2+r3))+((r4+r5)+(r6+r7))),
// then IEEE fp32 sqrt.
__global__ void k_prep(const float* __restrict__ xf, float* __restrict__ nrmf){
    int i = blockIdx.x*64 + threadIdx.x;
    const float* xr = xf + i*D;
    float r[8];
    #pragma unroll
    for (int q = 0; q < 8; ++q) r[q] = __fmul_rn(xr[q], xr[q]);
    #pragma unroll
    for (int b = 8; b < 64; b += 8)
        #pragma unroll
        for (int q = 0; q < 8; ++q)
            r[q] = __fadd_rn(r[q], __fmul_rn(xr[b+q], xr[b+q]));
    float s = __fadd_rn(__fadd_rn(__fadd_rn(r[0],r[1]), __fadd_rn(r[2],r[3])),
                        __fadd_rn(__fadd_rn(r[4],r[5]), __fadd_rn(r[6],r[7])));
    nrmf[i] = __fsqrt_rn(s);
}

// ---------------- topk: fp32 sims, bitwise-BLAS semantics ----------------
// dot = sequential fp32 FMA chain over k=0..63 (CPU sgemm microkernel order);
// sim = dot / (ni*nj + 1e-8) all fp32 IEEE. Rank by (value desc, index asc).
__global__ __launch_bounds__(256) void k_topk(const float* __restrict__ xf,
                                              const float* __restrict__ nrmf,
                                              int* __restrict__ topIdx,
                                              float* __restrict__ ewArr){
    __shared__ __align__(16) float xi[D];
    __shared__ float mv[4096];
    __shared__ int   mi[4096];
    __shared__ float swv[4];
    __shared__ int   swi[4];
    __shared__ int   swp[4];

    int i = blockIdx.x; int tid = threadIdx.x;
    if (tid < D) xi[tid] = xf[i*D + tid];
    __syncthreads();
    float ni = nrmf[i];

    float lv[16]; int li[16];
    #pragma unroll
    for (int r = 0; r < 16; ++r){ lv[r] = -3.0e38f; li[r] = INT_MAX; }

    for (int t = 0; t < N/256; ++t){
        int j = t*256 + tid;
        if (j == i) continue;
        const float4* xj4 = (const float4*)(xf + j*D);
        float acc = 0.0f;
        #pragma unroll
        for (int q = 0; q < 16; ++q){
            float4 a = xj4[q];
            acc = __fmaf_rn(a.x, xi[4*q+0], acc);
            acc = __fmaf_rn(a.y, xi[4*q+1], acc);
            acc = __fmaf_rn(a.z, xi[4*q+2], acc);
            acc = __fmaf_rn(a.w, xi[4*q+3], acc);
        }
        float nj = nrmf[j];
        float sim = __fdiv_rn(acc, __fadd_rn(__fmul_rn(ni, nj), 1e-8f));
        if (sim > lv[15]){
            lv[15] = sim; li[15] = j;
            #pragma unroll
            for (int r = 15; r > 0; --r){
                if (lv[r] > lv[r-1]){
                    float tv = lv[r]; lv[r] = lv[r-1]; lv[r-1] = tv;
                    int ti = li[r]; li[r] = li[r-1]; li[r-1] = ti;
                }
            }
        }
    }
    #pragma unroll
    for (int r = 0; r < 16; ++r){ mv[r*256 + tid] = lv[r]; mi[r*256 + tid] = li[r]; }
    __syncthreads();

    int wid = tid >> 6; int lane = tid & 63;
    for (int sel = 0; sel < 16; ++sel){
        float bv = -3.0e38f; int bi = INT_MAX; int bp = 0;
        #pragma unroll
        for (int r = 0; r < 16; ++r){
            int p = r*256 + tid;
            float v = mv[p]; int id = mi[p];
            if (v > bv || (v == bv && id < bi)){ bv = v; bi = id; bp = p; }
        }
        for (int off = 32; off > 0; off >>= 1){
            float ov = __shfl_down(bv, off);
            int   oi = __shfl_down(bi, off);
            int   op = __shfl_down(bp, off);
            if (ov > bv || (ov == bv && oi < bi)){ bv = ov; bi = oi; bp = op; }
        }
        if (lane == 0){ swv[wid] = bv; swi[wid] = bi; swp[wid] = bp; }
        __syncthreads();
        if (tid == 0){
            float fv = swv[0]; int fi = swi[0]; int fp = swp[0];
            for (int w = 1; w < 4; ++w){
                if (swv[w] > fv || (swv[w] == fv && swi[w] < fi)){
                    fv = swv[w]; fi = swi[w]; fp = swp[w];
                }
            }
            topIdx[i*KNB + sel] = fi;
            ewArr [i*KNB + sel] = (fv > 0.5f) ? fv : 0.0f;
            mv[fp] = -3.0e38f;
        }
        __syncthreads();
    }
}

// ---------------- degree / dinv ----------------
__global__ void k_deg_init(double* __restrict__ degD){
    int j = blockIdx.x*blockDim.x + threadIdx.x;
    if (j < N) degD[j] = 2.0;
}
__global__ void k_deg_scatter(const int* __restrict__ topIdx, const float* __restrict__ ewArr,
                              double* __restrict__ degD){
    int e = blockIdx.x*blockDim.x + threadIdx.x;
    if (e < NE){
        float w = ewArr[e];
        if (w > 0.0f) atomicAdd(&degD[topIdx[e]], (double)w);
    }
}
__global__ void k_dinv(const double* __restrict__ degD, float* __restrict__ dinv){
    int j = blockIdx.x*blockDim.x + threadIdx.x;
    if (j < N) dinv[j] = (float)(1.0 / sqrt(degD[j]));
}

// ---------------- dense matmuls ----------------
__global__ void k_gemm1(const float* __restrict__ xf, const float* __restrict__ W1,
                        float* __restrict__ h1){
    int id = blockIdx.x*256 + threadIdx.x;
    int i = id >> 7; int f = id & (H-1);
    const float* xr = xf + i*D;
    float acc = 0.f;
    #pragma unroll
    for (int k = 0; k < D; ++k) acc += xr[k] * W1[k*H + f];
    h1[id] = acc;
}
__global__ void k_gemm2(const float* __restrict__ z1, const float* __restrict__ W2,
                        float* __restrict__ h2){
    int id = blockIdx.x*256 + threadIdx.x;
    int i = id >> 6; int f = id & (O-1);
    const float* zr = z1 + i*H;
    float acc = 0.f;
    #pragma unroll
    for (int k = 0; k < H; ++k) acc += zr[k] * W2[k*O + f];
    h2[id] = acc;
}
__global__ void k_proj(const float* __restrict__ z2, const float* __restrict__ Wp,
                       const float* __restrict__ bp, float* __restrict__ z3){
    int id = blockIdx.x*256 + threadIdx.x;
    int i = id >> 6; int f = id & (D-1);
    const float* zr = z2 + i*O;
    float acc = bp[f];
    #pragma unroll
    for (int k = 0; k < O; ++k) acc += zr[k] * Wp[k*D + f];
    z3[id] = acc;
}

// ---------------- GCN aggregation ----------------
template<int F>
__global__ void k_agg_init(const float* __restrict__ h, const float* __restrict__ dinv,
                           float* __restrict__ agg){
    int id = blockIdx.x*256 + threadIdx.x;
    int j = id / F;
    float dj = dinv[j];
    agg[id] = 2.f * dj * dj * h[id];
}
template<int F>
__global__ void k_agg_scat(const int* __restrict__ topIdx, const float* __restrict__ ewArr,
                           const float* __restrict__ dinv, const float* __restrict__ h,
                           float* __restrict__ agg){
    int e = blockIdx.x; int f = threadIdx.x;
    float w = ewArr[e];
    if (w == 0.f) return;
    int s = e >> 4;
    int dn = topIdx[e];
    float c = dinv[s] * w * dinv[dn];
    atomicAdd(&agg[dn*F + f], c * h[s*F + f]);
}

// ---------------- bias + relu + layernorm ----------------
__global__ void k_post128(const float* __restrict__ agg, const float* __restrict__ b,
                          const float* __restrict__ g, const float* __restrict__ be,
                          float* __restrict__ z){
    __shared__ double s2[2];
    __shared__ double s3[2];
    int i = blockIdx.x; int f = threadIdx.x;
    float v = agg[i*H + f] + b[f];
    v = v > 0.f ? v : 0.f;
    int wid = f >> 6;
    double d = (double)v;
    for (int off = 32; off > 0; off >>= 1) d += __shfl_xor(d, off);
    if ((f & 63) == 0) s2[wid] = d;
    __syncthreads();
    double mu = (s2[0] + s2[1]) * (1.0/128.0);
    double dv = (double)v - mu;
    double q = dv * dv;
    for (int off = 32; off > 0; off >>= 1) q += __shfl_xor(q, off);
    if ((f & 63) == 0) s3[wid] = q;
    __syncthreads();
    double var = (s3[0] + s3[1]) * (1.0/128.0);
    double rs = 1.0 / sqrt(var + 1e-5);
    z[i*H + f] = (float)(dv * rs * (double)g[f] + (double)be[f]);
}
__global__ void k_post64(const float* __restrict__ agg, const float* __restrict__ b,
                         const float* __restrict__ g, const float* __restrict__ be,
                         float* __restrict__ z){
    int i = blockIdx.x; int f = threadIdx.x;
    float v = agg[i*O + f] + b[f];
    v = v > 0.f ? v : 0.f;
    double d = (double)v;
    for (int off = 32; off > 0; off >>= 1) d += __shfl_xor(d, off);
    double mu = d * (1.0/64.0);
    double dv = (double)v - mu;
    double q = dv * dv;
    for (int off = 32; off > 0; off >>= 1) q += __shfl_xor(q, off);
    double var = q * (1.0/64.0);
    double rs = 1.0 / sqrt(var + 1e-5);
    z[i*O + f] = (float)(dv * rs * (double)g[f] + (double)be[f]);
}

// ---------------- output stores (flag-branched dtype) ----------------
__global__ void k_store(const float* __restrict__ z3, void* __restrict__ outp,
                        const int* __restrict__ flag){
    int i = blockIdx.x*256 + threadIdx.x;
    float v = z3[i];
    if (*flag) ((unsigned short*)outp)[i] = f2bf(v);
    else       ((float*)outp)[i] = v;
}
__global__ void k_edges(const int* __restrict__ topIdx, const float* __restrict__ ewArr,
                        void* __restrict__ outp, const int* __restrict__ flag){
    int e = blockIdx.x*256 + threadIdx.x;
    if (e >= ETOT) return;
    int s, dn; float w;
    if (e < NE){ s = e >> 4; dn = topIdx[e]; w = ewArr[e]; }
    else       { s = e - NE; dn = s;        w = 1.0f; }
    if (*flag){
        unsigned short* o = (unsigned short*)outp;
        o[OUT0 + e]          = f2bf((float)s);
        o[OUT0 + ETOT + e]   = f2bf((float)dn);
        o[OUT0 + 2*ETOT + e] = f2bf(w);
    } else {
        float* o = (float*)outp;
        o[OUT0 + e]          = (float)s;
        o[OUT0 + ETOT + e]   = (float)dn;
        o[OUT0 + 2*ETOT + e] = w;
    }
}

extern "C" void kernel_launch(void* const* d_in, const int* in_sizes, int n_in,
                              void* d_out, int out_size, void* d_ws, size_t ws_size,
                              hipStream_t stream){
    char* ws = (char*)d_ws;
    int*    flag   = (int*)   (ws + 0);
    float*  w1f    = (float*) (ws + 4096);
    float*  b1f    = (float*) (ws + 36864);
    float*  g1f    = (float*) (ws + 37376);
    float*  be1f   = (float*) (ws + 37888);
    float*  w2f    = (float*) (ws + 38400);
    float*  b2f    = (float*) (ws + 71168);
    float*  g2f    = (float*) (ws + 71424);
    float*  be2f   = (float*) (ws + 71680);
    float*  wpf    = (float*) (ws + 71936);
    float*  bpf    = (float*) (ws + 88320);
    float*  xf     = (float*) (ws + 98304);      // 2 MB          -> 2195456
    float*  nrmf   = (float*) (ws + 2195456);    // 32 KB         -> 2228224 (pad to 2260992)
    int*    topIdx = (int*)   (ws + 2260992);    // 512 KB        -> 2785280
    float*  ewArr  = (float*) (ws + 2785280);    // 512 KB        -> 3309568
    double* degD   = (double*)(ws + 3309568);    // 64 KB         -> 3375104
    float*  dinv   = (float*) (ws + 3375104);    // 32 KB         -> 3407872
    float*  h1     = (float*) (ws + 3407872);    // 4 MB          -> 7602176
    float*  agg1   = (float*) (ws + 7602176);    // 4 MB          -> 11796480
    float*  z1     = (float*) (ws + 11796480);   // 4 MB          -> 15990784
    float*  h2     = h1;
    float*  agg2   = agg1;
    float*  z2     = z1;
    float*  z3     = h1;

    k_probe<<<1, 256, 0, stream>>>((const unsigned short*)d_in[0], flag);
    k_cvt<<<(N*D+255)/256, 256, 0, stream>>>(d_in[0], xf,  N*D, flag);
    k_cvt<<<(D*H+255)/256, 256, 0, stream>>>(d_in[1], w1f, D*H, flag);
    k_cvt<<<1, 256, 0, stream>>>(d_in[2], b1f,  H, flag);
    k_cvt<<<1, 256, 0, stream>>>(d_in[3], g1f,  H, flag);
    k_cvt<<<1, 256, 0, stream>>>(d_in[4], be1f, H, flag);
    k_cvt<<<(H*O+255)/256, 256, 0, stream>>>(d_in[5], w2f, H*O, flag);
    k_cvt<<<1, 256, 0, stream>>>(d_in[6], b2f,  O, flag);
    k_cvt<<<1, 256, 0, stream>>>(d_in[7], g2f,  O, flag);
    k_cvt<<<1, 256, 0, stream>>>(d_in[8], be2f, O, flag);
    k_cvt<<<(O*D+255)/256, 256, 0, stream>>>(d_in[9], wpf, O*D, flag);
    k_cvt<<<1, 256, 0, stream>>>(d_in[10], bpf, D, flag);

    k_prep<<<N/64, 64, 0, stream>>>(xf, nrmf);
    k_topk<<<N, 256, 0, stream>>>(xf, nrmf, topIdx, ewArr);
    k_deg_init<<<N/256, 256, 0, stream>>>(degD);
    k_deg_scatter<<<NE/256, 256, 0, stream>>>(topIdx, ewArr, degD);
    k_dinv<<<N/256, 256, 0, stream>>>(degD, dinv);

    k_gemm1<<<(N*H)/256, 256, 0, stream>>>(xf, w1f, h1);
    k_agg_init<H><<<(N*H)/256, 256, 0, stream>>>(h1, dinv, agg1);
    k_agg_scat<H><<<NE, H, 0, stream>>>(topIdx, ewArr, dinv, h1, agg1);
    k_post128<<<N, H, 0, stream>>>(agg1, b1f, g1f, be1f, z1);

    k_gemm2<<<(N*O)/256, 256, 0, stream>>>(z1, w2f, h2);
    k_agg_init<O><<<(N*O)/256, 256, 0, stream>>>(h2, dinv, agg2);
    k_agg_scat<O><<<NE, O, 0, stream>>>(topIdx, ewArr, dinv, h2, agg2);
    k_post64<<<N, O, 0, stream>>>(agg2, b2f, g2f, be2f, z2);

    k_proj<<<(N*D)/256, 256, 0, stream>>>(z2, wpf, bpf, z3);
    k_store<<<(N*D)/256, 256, 0, stream>>>(z3, d_out, flag);
    k_edges<<<(ETOT+255)/256, 256, 0, stream>>>(topIdx, ewArr, d_out, flag);
}

// Round 4
// 852.797 us; speedup vs baseline: 2.3984x; 2.3984x over previous
//
#include <hip/hip_runtime.h>
#include <cstdint>
#include <climits>

#define N 8192
#define D 64
#define H 128
#define O 64
#define KNB 16
#define NE (N*KNB)        // 131072
#define ETOT (NE + N)     // 139264
#define OUT0 (N*D)        // 524288

__device__ __forceinline__ float bf2f(unsigned short u){
    union { unsigned int u; float f; } v; v.u = ((unsigned int)u) << 16; return v.f;
}
__device__ __forceinline__ unsigned short f2bf(float f){
    union { float f; unsigned int u; } v; v.f = f;
    unsigned int r = v.u + 0x7FFFu + ((v.u >> 16) & 1u);   // RNE
    return (unsigned short)(r >> 16);
}

// ---------------- dtype probe: 1=bf16 inputs, 0=fp32 inputs ----------------
__global__ void k_probe(const unsigned short* __restrict__ x, int* __restrict__ flag){
    __shared__ int cnt;
    if (threadIdx.x == 0) cnt = 0;
    __syncthreads();
    unsigned short u = x[2*threadIdx.x];
    int e = (u >> 7) & 0xFF;
    int ok = (u == 0) || (e >= 0x60 && e <= 0x85);
    unsigned long long m = __ballot(ok);
    if ((threadIdx.x & 63) == 0) atomicAdd(&cnt, __popcll(m));
    __syncthreads();
    if (threadIdx.x == 0) *flag = (cnt >= 128) ? 1 : 0;
}

// ---------------- generic input convert -> fp32 ----------------
__global__ void k_cvt(const void* __restrict__ src, float* __restrict__ dst,
                      int n, const int* __restrict__ flag){
    int i = blockIdx.x*256 + threadIdx.x;
    if (i >= n) return;
    if (*flag) dst[i] = bf2f(((const unsigned short*)src)[i]);
    else       dst[i] = ((const float*)src)[i];
}

// ---------------- row norms: EXACT numpy fp32 pairwise semantics ----------------
__global__ void k_prep(const float* __restrict__ xf, float* __restrict__ nrmf){
    int i = blockIdx.x*64 + threadIdx.x;
    const float* xr = xf + i*D;
    float r[8];
    #pragma unroll
    for (int q = 0; q < 8; ++q) r[q] = __fmul_rn(xr[q], xr[q]);
    #pragma unroll
    for (int b = 8; b < 64; b += 8)
        #pragma unroll
        for (int q = 0; q < 8; ++q)
            r[q] = __fadd_rn(r[q], __fmul_rn(xr[b+q], xr[b+q]));
    float s = __fadd_rn(__fadd_rn(__fadd_rn(r[0],r[1]), __fadd_rn(r[2],r[3])),
                        __fadd_rn(__fadd_rn(r[4],r[5]), __fadd_rn(r[6],r[7])));
    nrmf[i] = __fsqrt_rn(s);
}

// ---------------- topk: 16 queries/block, 2-way j-interleaved fp32 chains ----
// Thread (q = tid&15, m = tid>>4): query i = blk*16+q, scans j = m+16t.
// xi row held in 64 VGPRs; two independent FMA chains per iteration for ILP.
// Sim semantics bitwise-identical to R3 (sequential fp32 FMA k=0..63,
// sim = dot/(ni*nj+1e-8), rank by value desc / index asc).
__global__ __launch_bounds__(256) void k_topk(const float* __restrict__ xf,
                                              const float* __restrict__ nrmf,
                                              int* __restrict__ topIdx,
                                              float* __restrict__ ewArr){
    __shared__ float mv[4096];   // pool: [q*256 + m*16 + r]
    __shared__ int   mi[4096];
    __shared__ float cv[256];    // per-round candidates [q*16 + m]
    __shared__ int   ci[256];
    __shared__ int   cp[256];

    int tid = threadIdx.x;
    int q = tid & 15, m = tid >> 4;
    int i = blockIdx.x*16 + q;

    const float4* xip = (const float4*)(xf + (size_t)i*D);
    float4 xi4[16];
    #pragma unroll
    for (int c = 0; c < 16; ++c) xi4[c] = xip[c];
    float ni = nrmf[i];

    float lv[16]; int li[16];
    #pragma unroll
    for (int r = 0; r < 16; ++r){ lv[r] = -3.0e38f; li[r] = INT_MAX; }

    for (int s = 0; s < 256; ++s){
        int j0 = m + 32*s;
        int j1 = j0 + 16;
        const float4* A0 = (const float4*)(xf + (size_t)j0*D);
        const float4* A1 = (const float4*)(xf + (size_t)j1*D);
        float a0 = 0.0f, a1 = 0.0f;
        #pragma unroll
        for (int c = 0; c < 16; ++c){
            float4 b0 = A0[c], b1 = A1[c], xa = xi4[c];
            a0 = __fmaf_rn(b0.x, xa.x, a0);
            a0 = __fmaf_rn(b0.y, xa.y, a0);
            a0 = __fmaf_rn(b0.z, xa.z, a0);
            a0 = __fmaf_rn(b0.w, xa.w, a0);
            a1 = __fmaf_rn(b1.x, xa.x, a1);
            a1 = __fmaf_rn(b1.y, xa.y, a1);
            a1 = __fmaf_rn(b1.z, xa.z, a1);
            a1 = __fmaf_rn(b1.w, xa.w, a1);
        }
        float s0 = __fdiv_rn(a0, __fadd_rn(__fmul_rn(ni, nrmf[j0]), 1e-8f));
        float s1 = __fdiv_rn(a1, __fadd_rn(__fmul_rn(ni, nrmf[j1]), 1e-8f));
        if (j0 == i) s0 = -3.0e38f;
        if (j1 == i) s1 = -3.0e38f;
        if (s0 > lv[15]){
            lv[15] = s0; li[15] = j0;
            #pragma unroll
            for (int r = 15; r > 0; --r){
                if (lv[r] > lv[r-1]){
                    float tv = lv[r]; lv[r] = lv[r-1]; lv[r-1] = tv;
                    int ti = li[r]; li[r] = li[r-1]; li[r-1] = ti;
                }
            }
        }
        if (s1 > lv[15]){
            lv[15] = s1; li[15] = j1;
            #pragma unroll
            for (int r = 15; r > 0; --r){
                if (lv[r] > lv[r-1]){
                    float tv = lv[r]; lv[r] = lv[r-1]; lv[r-1] = tv;
                    int ti = li[r]; li[r] = li[r-1]; li[r-1] = ti;
                }
            }
        }
    }

    #pragma unroll
    for (int r = 0; r < 16; ++r){
        mv[q*256 + m*16 + r] = lv[r];
        mi[q*256 + m*16 + r] = li[r];
    }
    __syncthreads();

    for (int sel = 0; sel < 16; ++sel){
        float bv = -3.0e38f; int bi = INT_MAX; int bp = 0;
        #pragma unroll
        for (int r = 0; r < 16; ++r){
            int p = q*256 + m*16 + r;
            float v = mv[p]; int id = mi[p];
            if (v > bv || (v == bv && id < bi)){ bv = v; bi = id; bp = p; }
        }
        cv[q*16 + m] = bv; ci[q*16 + m] = bi; cp[q*16 + m] = bp;
        __syncthreads();
        if (tid < 16){
            int q2 = tid;
            float fv = -3.0e38f; int fi = INT_MAX; int fp = 0;
            #pragma unroll
            for (int c = 0; c < 16; ++c){
                float v = cv[q2*16 + c]; int id = ci[q2*16 + c];
                if (v > fv || (v == fv && id < fi)){ fv = v; fi = id; fp = cp[q2*16 + c]; }
            }
            int i2 = blockIdx.x*16 + q2;
            topIdx[i2*KNB + sel] = fi;
            ewArr [i2*KNB + sel] = (fv > 0.5f) ? fv : 0.0f;
            mv[fp] = -3.0e38f;
        }
        __syncthreads();
    }
}

// ---------------- degree / dinv ----------------
__global__ void k_deg_init(double* __restrict__ degD){
    int j = blockIdx.x*blockDim.x + threadIdx.x;
    if (j < N) degD[j] = 2.0;
}
__global__ void k_deg_scatter(const int* __restrict__ topIdx, const float* __restrict__ ewArr,
                              double* __restrict__ degD){
    int e = blockIdx.x*blockDim.x + threadIdx.x;
    if (e < NE){
        float w = ewArr[e];
        if (w > 0.0f) atomicAdd(&degD[topIdx[e]], (double)w);
    }
}
__global__ void k_dinv(const double* __restrict__ degD, float* __restrict__ dinv){
    int j = blockIdx.x*blockDim.x + threadIdx.x;
    if (j < N) dinv[j] = (float)(1.0 / sqrt(degD[j]));
}

// ---------------- dense matmuls ----------------
__global__ void k_gemm1(const float* __restrict__ xf, const float* __restrict__ W1,
                        float* __restrict__ h1){
    int id = blockIdx.x*256 + threadIdx.x;
    int i = id >> 7; int f = id & (H-1);
    const float* xr = xf + i*D;
    float acc = 0.f;
    #pragma unroll
    for (int k = 0; k < D; ++k) acc += xr[k] * W1[k*H + f];
    h1[id] = acc;
}
__global__ void k_gemm2(const float* __restrict__ z1, const float* __restrict__ W2,
                        float* __restrict__ h2){
    int id = blockIdx.x*256 + threadIdx.x;
    int i = id >> 6; int f = id & (O-1);
    const float* zr = z1 + i*H;
    float acc = 0.f;
    #pragma unroll
    for (int k = 0; k < H; ++k) acc += zr[k] * W2[k*O + f];
    h2[id] = acc;
}
__global__ void k_proj(const float* __restrict__ z2, const float* __restrict__ Wp,
                       const float* __restrict__ bp, float* __restrict__ z3){
    int id = blockIdx.x*256 + threadIdx.x;
    int i = id >> 6; int f = id & (D-1);
    const float* zr = z2 + i*O;
    float acc = bp[f];
    #pragma unroll
    for (int k = 0; k < O; ++k) acc += zr[k] * Wp[k*D + f];
    z3[id] = acc;
}

// ---------------- GCN aggregation ----------------
template<int F>
__global__ void k_agg_init(const float* __restrict__ h, const float* __restrict__ dinv,
                           float* __restrict__ agg){
    int id = blockIdx.x*256 + threadIdx.x;
    int j = id / F;
    float dj = dinv[j];
    agg[id] = 2.f * dj * dj * h[id];
}
template<int F>
__global__ void k_agg_scat(const int* __restrict__ topIdx, const float* __restrict__ ewArr,
                           const float* __restrict__ dinv, const float* __restrict__ h,
                           float* __restrict__ agg){
    int e = blockIdx.x; int f = threadIdx.x;
    float w = ewArr[e];
    if (w == 0.f) return;
    int s = e >> 4;
    int dn = topIdx[e];
    float c = dinv[s] * w * dinv[dn];
    atomicAdd(&agg[dn*F + f], c * h[s*F + f]);
}

// ---------------- bias + relu + layernorm ----------------
__global__ void k_post128(const float* __restrict__ agg, const float* __restrict__ b,
                          const float* __restrict__ g, const float* __restrict__ be,
                          float* __restrict__ z){
    __shared__ double s2[2];
    __shared__ double s3[2];
    int i = blockIdx.x; int f = threadIdx.x;
    float v = agg[i*H + f] + b[f];
    v = v > 0.f ? v : 0.f;
    int wid = f >> 6;
    double d = (double)v;
    for (int off = 32; off > 0; off >>= 1) d += __shfl_xor(d, off);
    if ((f & 63) == 0) s2[wid] = d;
    __syncthreads();
    double mu = (s2[0] + s2[1]) * (1.0/128.0);
    double dv = (double)v - mu;
    double qq = dv * dv;
    for (int off = 32; off > 0; off >>= 1) qq += __shfl_xor(qq, off);
    if ((f & 63) == 0) s3[wid] = qq;
    __syncthreads();
    double var = (s3[0] + s3[1]) * (1.0/128.0);
    double rs = 1.0 / sqrt(var + 1e-5);
    z[i*H + f] = (float)(dv * rs * (double)g[f] + (double)be[f]);
}
__global__ void k_post64(const float* __restrict__ agg, const float* __restrict__ b,
                         const float* __restrict__ g, const float* __restrict__ be,
                         float* __restrict__ z){
    int i = blockIdx.x; int f = threadIdx.x;
    float v = agg[i*O + f] + b[f];
    v = v > 0.f ? v : 0.f;
    double d = (double)v;
    for (int off = 32; off > 0; off >>= 1) d += __shfl_xor(d, off);
    double mu = d * (1.0/64.0);
    double dv = (double)v - mu;
    double qq = dv * dv;
    for (int off = 32; off > 0; off >>= 1) qq += __shfl_xor(qq, off);
    double var = qq * (1.0/64.0);
    double rs = 1.0 / sqrt(var + 1e-5);
    z[i*O + f] = (float)(dv * rs * (double)g[f] + (double)be[f]);
}

// ---------------- output stores (flag-branched dtype) ----------------
__global__ void k_store(const float* __restrict__ z3, void* __restrict__ outp,
                        const int* __restrict__ flag){
    int i = blockIdx.x*256 + threadIdx.x;
    float v = z3[i];
    if (*flag) ((unsigned short*)outp)[i] = f2bf(v);
    else       ((float*)outp)[i] = v;
}
__global__ void k_edges(const int* __restrict__ topIdx, const float* __restrict__ ewArr,
                        void* __restrict__ outp, const int* __restrict__ flag){
    int e = blockIdx.x*256 + threadIdx.x;
    if (e >= ETOT) return;
    int s, dn; float w;
    if (e < NE){ s = e >> 4; dn = topIdx[e]; w = ewArr[e]; }
    else       { s = e - NE; dn = s;        w = 1.0f; }
    if (*flag){
        unsigned short* o = (unsigned short*)outp;
        o[OUT0 + e]          = f2bf((float)s);
        o[OUT0 + ETOT + e]   = f2bf((float)dn);
        o[OUT0 + 2*ETOT + e] = f2bf(w);
    } else {
        float* o = (float*)outp;
        o[OUT0 + e]          = (float)s;
        o[OUT0 + ETOT + e]   = (float)dn;
        o[OUT0 + 2*ETOT + e] = w;
    }
}

extern "C" void kernel_launch(void* const* d_in, const int* in_sizes, int n_in,
                              void* d_out, int out_size, void* d_ws, size_t ws_size,
                              hipStream_t stream){
    char* ws = (char*)d_ws;
    int*    flag   = (int*)   (ws + 0);
    float*  w1f    = (float*) (ws + 4096);
    float*  b1f    = (float*) (ws + 36864);
    float*  g1f    = (float*) (ws + 37376);
    float*  be1f   = (float*) (ws + 37888);
    float*  w2f    = (float*) (ws + 38400);
    float*  b2f    = (float*) (ws + 71168);
    float*  g2f    = (float*) (ws + 71424);
    float*  be2f   = (float*) (ws + 71680);
    float*  wpf    = (float*) (ws + 71936);
    float*  bpf    = (float*) (ws + 88320);
    float*  xf     = (float*) (ws + 98304);      // 2 MB          -> 2195456
    float*  nrmf   = (float*) (ws + 2195456);    // 32 KB         -> 2228224
    int*    topIdx = (int*)   (ws + 2260992);    // 512 KB        -> 2785280
    float*  ewArr  = (float*) (ws + 2785280);    // 512 KB        -> 3309568
    double* degD   = (double*)(ws + 3309568);    // 64 KB         -> 3375104
    float*  dinv   = (float*) (ws + 3375104);    // 32 KB         -> 3407872
    float*  h1     = (float*) (ws + 3407872);    // 4 MB          -> 7602176
    float*  agg1   = (float*) (ws + 7602176);    // 4 MB          -> 11796480
    float*  z1     = (float*) (ws + 11796480);   // 4 MB          -> 15990784
    float*  h2     = h1;
    float*  agg2   = agg1;
    float*  z2     = z1;
    float*  z3     = h1;

    k_probe<<<1, 256, 0, stream>>>((const unsigned short*)d_in[0], flag);
    k_cvt<<<(N*D+255)/256, 256, 0, stream>>>(d_in[0], xf,  N*D, flag);
    k_cvt<<<(D*H+255)/256, 256, 0, stream>>>(d_in[1], w1f, D*H, flag);
    k_cvt<<<1, 256, 0, stream>>>(d_in[2], b1f,  H, flag);
    k_cvt<<<1, 256, 0, stream>>>(d_in[3], g1f,  H, flag);
    k_cvt<<<1, 256, 0, stream>>>(d_in[4], be1f, H, flag);
    k_cvt<<<(H*O+255)/256, 256, 0, stream>>>(d_in[5], w2f, H*O, flag);
    k_cvt<<<1, 256, 0, stream>>>(d_in[6], b2f,  O, flag);
    k_cvt<<<1, 256, 0, stream>>>(d_in[7], g2f,  O, flag);
    k_cvt<<<1, 256, 0, stream>>>(d_in[8], be2f, O, flag);
    k_cvt<<<(O*D+255)/256, 256, 0, stream>>>(d_in[9], wpf, O*D, flag);
    k_cvt<<<1, 256, 0, stream>>>(d_in[10], bpf, D, flag);

    k_prep<<<N/64, 64, 0, stream>>>(xf, nrmf);
    k_topk<<<N/16, 256, 0, stream>>>(xf, nrmf, topIdx, ewArr);
    k_deg_init<<<N/256, 256, 0, stream>>>(degD);
    k_deg_scatter<<<NE/256, 256, 0, stream>>>(topIdx, ewArr, degD);
    k_dinv<<<N/256, 256, 0, stream>>>(degD, dinv);

    k_gemm1<<<(N*H)/256, 256, 0, stream>>>(xf, w1f, h1);
    k_agg_init<H><<<(N*H)/256, 256, 0, stream>>>(h1, dinv, agg1);
    k_agg_scat<H><<<NE, H, 0, stream>>>(topIdx, ewArr, dinv, h1, agg1);
    k_post128<<<N, H, 0, stream>>>(agg1, b1f, g1f, be1f, z1);

    k_gemm2<<<(N*O)/256, 256, 0, stream>>>(z1, w2f, h2);
    k_agg_init<O><<<(N*O)/256, 256, 0, stream>>>(h2, dinv, agg2);
    k_agg_scat<O><<<NE, O, 0, stream>>>(topIdx, ewArr, dinv, h2, agg2);
    k_post64<<<N, O, 0, stream>>>(agg2, b2f, g2f, be2f, z2);

    k_proj<<<(N*D)/256, 256, 0, stream>>>(z2, wpf, bpf, z3);
    k_store<<<(N*D)/256, 256, 0, stream>>>(z3, d_out, flag);
    k_edges<<<(ETOT+255)/256, 256, 0, stream>>>(topIdx, ewArr, d_out, flag);
}